// Round 1
// baseline (19970.140 us; speedup 1.0000x reference)
//
#include <hip/hip_runtime.h>
#include <hip/hip_bf16.h>

// ---------------------------------------------------------------------------
// 2-layer GRU, H=1200, B=64, T=512, I=30. Output = [h_last_layer0, h_last_layer1]
// Strategy: bf16-split (hi+lo) MFMA for all K=1200 matmuls, fp32 state.
// 513 fused step launches: blocks [0,300) = layer0 step s, [300,600) = layer1 step s-1.
// ---------------------------------------------------------------------------

#define Hh 1200
#define HP 1216      // K padded to 38*32
#define TT 512
#define BB 64
#define II 30
#define KS_TOT 38    // HP/32
#define KS_HALF 19
#define KCH 608      // 19*32
#define NTG 75       // 1200/16 gate-column tiles
#define NBLK_L 300   // 4 M-tiles * 75 N-tiles
#define LSTR 616     // LDS row stride (608 + 8 pad) in bf16 elems

typedef __attribute__((ext_vector_type(8))) short short8;
typedef __attribute__((ext_vector_type(4))) float f32x4;

// workspace layout (bytes)
#define SZ_WF 17510400ull            // 225*38*2*512 bf16 elems * 2B
#define OFF_WHH0 0ull
#define OFF_WIH1 17510400ull
#define OFF_WHH1 35020800ull
#define OFF_STATE 52531200ull
#define SZ_HF 307200ull              // 64*1200 fp32
#define SZ_HB 155648ull              // 64*1216 bf16
#define OFF_XF OFF_STATE
#define OFF_YF (OFF_STATE + 2ull*SZ_HF)
#define OFF_XB (OFF_STATE + 4ull*SZ_HF)
#define OFF_YB (OFF_XB + 2ull*SZ_HB)
#define WS_NEEDED (OFF_YB + 2ull*SZ_HB)
#define STATE_U128 115712            // (4*SZ_HF + 4*SZ_HB)/16

__device__ __forceinline__ unsigned short f2bf(float f){
  unsigned u = __float_as_uint(f);
  unsigned r = u + 0x7FFFu + ((u >> 16) & 1u);   // round-to-nearest-even
  return (unsigned short)(r >> 16);
}
__device__ __forceinline__ float bf2f(unsigned short s){
  return __uint_as_float(((unsigned)s) << 16);
}
__device__ __forceinline__ float sigmoid_f(float v){ return 1.f/(1.f + __expf(-v)); }
__device__ __forceinline__ float tanh_f(float v){ float e = __expf(2.f*v); return 1.f - 2.f/(e + 1.f); }

// Split W[3600][1200] fp32 -> bf16 hi/lo in MFMA B-fragment order.
// chunk (nt,ks,split): 64 lanes * 8 bf16; lane l holds W[nt*16+(l&15)][ks*32+(l>>4)*8 + 0..7]
__global__ void prep_w(const float* __restrict__ W, unsigned short* __restrict__ Wf){
  int blk = blockIdx.x;
  int nt = blk / KS_TOT, ks = blk - nt*KS_TOT;
  int l = threadIdx.x;
  int n = nt*16 + (l & 15);
  int k0 = ks*32 + (l >> 4)*8;
  alignas(16) unsigned short hi[8];
  alignas(16) unsigned short lo[8];
  #pragma unroll
  for (int j = 0; j < 8; j++){
    int k = k0 + j;
    float w = (k < Hh) ? W[(size_t)n*Hh + k] : 0.f;
    unsigned short h16 = f2bf(w);
    hi[j] = h16;
    lo[j] = f2bf(w - bf2f(h16));
  }
  size_t cbase = ((size_t)(nt*KS_TOT + ks))*2ull*512ull;
  *(short8*)(Wf + cbase + (size_t)l*8)        = *(const short8*)hi;
  *(short8*)(Wf + cbase + 512 + (size_t)l*8)  = *(const short8*)lo;
}

__global__ void init_state(char* __restrict__ ws){
  size_t i = (size_t)blockIdx.x*256 + threadIdx.x;
  if (i < STATE_U128){
    f32x4 z = {0.f,0.f,0.f,0.f};
    ((f32x4*)(ws + OFF_STATE))[i] = z;
  }
}

__global__ void __launch_bounds__(192) gru_step(
    char* __restrict__ ws,
    const float* __restrict__ x,
    const float* __restrict__ Wih0,
    const float* __restrict__ bih0, const float* __restrict__ bhh0,
    const float* __restrict__ bih1, const float* __restrict__ bhh1,
    int s)
{
  const int bid = blockIdx.x;
  const int layer = bid >= NBLK_L;
  if (!layer && s == TT) return;   // last launch: only layer1 active
  if (layer && s == 0)  return;    // first launch: only layer0 active
  const int t = layer ? (s - 1) : s;
  const int lb = layer ? (bid - NBLK_L) : bid;
  const int mt = lb / NTG;               // batch tile 0..3
  const int nb = lb - mt*NTG;            // gate-column tile 0..74
  const int wave = threadIdx.x >> 6;     // 0=r 1=z 2=n
  const int lane = threadIdx.x & 63;
  const int col  = lane & 15;
  const int kg   = lane >> 4;
  const int par  = t & 1;

  const unsigned short* Wfhh = (const unsigned short*)(ws + (layer ? OFF_WHH1 : OFF_WHH0));
  const unsigned short* Wfih = (const unsigned short*)(ws + OFF_WIH1);
  const float* hf_in  = (const float*)(ws + (layer ? OFF_YF : OFF_XF) + (size_t)par*SZ_HF);
  float*       hf_out = (float*)      (ws + (layer ? OFF_YF : OFF_XF) + (size_t)(par^1)*SZ_HF);
  const unsigned short* hbf_in  = (const unsigned short*)(ws + (layer ? OFF_YB : OFF_XB) + (size_t)par*SZ_HB);
  unsigned short*       hbf_out = (unsigned short*)      (ws + (layer ? OFF_YB : OFF_XB) + (size_t)(par^1)*SZ_HB);
  // layer1 A-operand for the input-side matmul: out0[t] = h0 state written at launch s-1
  const unsigned short* xbf_in  = (const unsigned short*)(ws + OFF_XB + (size_t)(par^1)*SZ_HB);
  const float* bih = layer ? bih1 : bih0;
  const float* bhh = layer ? bhh1 : bhh0;

  __shared__ alignas(16) unsigned short hA[16][LSTR];
  __shared__ alignas(16) unsigned short xAs[16][LSTR];
  __shared__ float xl[16][II];
  __shared__ float rz[2][16][17];

  if (!layer){
    for (int i = threadIdx.x; i < 16*II; i += 192){
      int r = i / II, c = i - r*II;
      xl[r][c] = x[((size_t)(mt*16 + r)*TT + t)*II + c];
    }
  }

  f32x4 acc_h0 = {0.f,0.f,0.f,0.f};
  f32x4 acc_h1 = {0.f,0.f,0.f,0.f};
  f32x4 acc_x0 = {0.f,0.f,0.f,0.f};
  f32x4 acc_x1 = {0.f,0.f,0.f,0.f};
  const int ntW = wave*NTG + nb;         // row-tile of W (gate matrix offset folded in)

  for (int ch = 0; ch < 2; ch++){
    __syncthreads();
    for (int i = threadIdx.x; i < 16*(KCH/8); i += 192){
      int r = i / (KCH/8), c8 = i - r*(KCH/8);
      *(short8*)&hA[r][c8*8] =
        *(const short8*)&hbf_in[(size_t)(mt*16 + r)*HP + ch*KCH + c8*8];
    }
    if (layer){
      for (int i = threadIdx.x; i < 16*(KCH/8); i += 192){
        int r = i / (KCH/8), c8 = i - r*(KCH/8);
        *(short8*)&xAs[r][c8*8] =
          *(const short8*)&xbf_in[(size_t)(mt*16 + r)*HP + ch*KCH + c8*8];
      }
    }
    __syncthreads();

    const short8* wb  = (const short8*)Wfhh + ((size_t)(ntW*KS_TOT + ch*KS_HALF))*2*64 + lane;
    if (!layer){
      for (int ksl = 0; ksl < KS_HALF; ksl++){
        short8 a = *(const short8*)&hA[col][ksl*32 + kg*8];
        acc_h0 = __builtin_amdgcn_mfma_f32_16x16x32_bf16(a, wb[0],  acc_h0, 0, 0, 0);
        acc_h1 = __builtin_amdgcn_mfma_f32_16x16x32_bf16(a, wb[64], acc_h1, 0, 0, 0);
        wb += 128;
      }
    } else {
      const short8* wbx = (const short8*)Wfih + ((size_t)(ntW*KS_TOT + ch*KS_HALF))*2*64 + lane;
      for (int ksl = 0; ksl < KS_HALF; ksl++){
        short8 a  = *(const short8*)&hA[col][ksl*32 + kg*8];
        short8 ax = *(const short8*)&xAs[col][ksl*32 + kg*8];
        acc_h0 = __builtin_amdgcn_mfma_f32_16x16x32_bf16(a,  wb[0],   acc_h0, 0, 0, 0);
        acc_h1 = __builtin_amdgcn_mfma_f32_16x16x32_bf16(a,  wb[64],  acc_h1, 0, 0, 0);
        acc_x0 = __builtin_amdgcn_mfma_f32_16x16x32_bf16(ax, wbx[0],  acc_x0, 0, 0, 0);
        acc_x1 = __builtin_amdgcn_mfma_f32_16x16x32_bf16(ax, wbx[64], acc_x1, 0, 0, 0);
        wb += 128; wbx += 128;
      }
    }
  }

  f32x4 gh = acc_h0 + acc_h1;   // h-side gate pre-activations (no bias yet)
  f32x4 gx;                     // input-side
  if (layer){
    gx = acc_x0 + acc_x1;
  } else {
    // exact fp32 gi for layer0 (K=30)
    float wr[II];
    int wrow = wave*Hh + nb*16 + col;
    #pragma unroll
    for (int i = 0; i < II; i++) wr[i] = Wih0[(size_t)wrow*II + i];
    #pragma unroll
    for (int j = 0; j < 4; j++){
      float sacc = 0.f;
      #pragma unroll
      for (int i = 0; i < II; i++) sacc += wr[i]*xl[kg*4 + j][i];
      gx[j] = sacc;
    }
  }

  const int gidx = wave*Hh + nb*16 + col;
  const float bI = bih[gidx], bH = bhh[gidx];

  if (wave < 2){
    #pragma unroll
    for (int j = 0; j < 4; j++){
      float pre = gh[j] + gx[j] + bI + bH;
      rz[wave][kg*4 + j][col] = sigmoid_f(pre);
    }
  }
  __syncthreads();
  if (wave == 2){
    #pragma unroll
    for (int j = 0; j < 4; j++){
      int rr = kg*4 + j;
      int b  = mt*16 + rr;
      int hcol = nb*16 + col;
      float rg = rz[0][rr][col];
      float zg = rz[1][rr][col];
      float ng = tanh_f(gx[j] + bI + rg*(gh[j] + bH));
      float hold = hf_in[(size_t)b*Hh + hcol];
      float hn = (1.f - zg)*ng + zg*hold;
      hf_out[(size_t)b*Hh + hcol] = hn;
      hbf_out[(size_t)b*HP + hcol] = f2bf(hn);
    }
  }
}

__global__ void write_out(const char* __restrict__ ws, float* __restrict__ out){
  int i = blockIdx.x*256 + threadIdx.x;
  if (i < 76800)        out[i] = *(const float*)(ws + OFF_XF + (size_t)i*4);
  else if (i < 153600)  out[i] = *(const float*)(ws + OFF_YF + (size_t)(i - 76800)*4);
}

extern "C" void kernel_launch(void* const* d_in, const int* in_sizes, int n_in,
                              void* d_out, int out_size, void* d_ws, size_t ws_size,
                              hipStream_t stream)
{
  const float* x    = (const float*)d_in[0];
  const float* Wih0 = (const float*)d_in[1];
  const float* Whh0 = (const float*)d_in[2];
  const float* bih0 = (const float*)d_in[3];
  const float* bhh0 = (const float*)d_in[4];
  const float* Wih1 = (const float*)d_in[5];
  const float* Whh1 = (const float*)d_in[6];
  const float* bih1 = (const float*)d_in[7];
  const float* bhh1 = (const float*)d_in[8];
  char* ws = (char*)d_ws;
  if (ws_size < WS_NEEDED) return;   // need ~54.4 MB scratch

  dim3 pgrid(225*KS_TOT);
  prep_w<<<pgrid, 64, 0, stream>>>(Whh0, (unsigned short*)(ws + OFF_WHH0));
  prep_w<<<pgrid, 64, 0, stream>>>(Wih1, (unsigned short*)(ws + OFF_WIH1));
  prep_w<<<pgrid, 64, 0, stream>>>(Whh1, (unsigned short*)(ws + OFF_WHH1));
  init_state<<<452, 256, 0, stream>>>(ws);

  for (int s = 0; s <= TT; s++)
    gru_step<<<600, 192, 0, stream>>>(ws, x, Wih0, bih0, bhh0, bih1, bhh1, s);

  write_out<<<600, 256, 0, stream>>>(ws, (float*)d_out);
}

// Round 2
// 18512.430 us; speedup vs baseline: 1.0787x; 1.0787x over previous
//
#include <hip/hip_runtime.h>
#include <hip/hip_bf16.h>

// ---------------------------------------------------------------------------
// 2-layer GRU, H=1200, B=64, T=512, I=30. Output = [h_last_l0, h_last_l1].
// R2: 225-block/step layout, weights read ONCE per step (52.5 MB/step min),
// M=64 per block with 4x register reuse of weight fragments. Layer1 split into
// gx-stage (W_ih1) and gh+fuse-stage (W_hh1), pipelined one launch apart.
// ---------------------------------------------------------------------------

#define Hh 1200
#define HP 1216      // K padded to 38*32
#define TT 512
#define II 30
#define KS_TOT 38
#define KS_HALF 19
#define KCH 608
#define NTG 75       // 1200/16 column tiles
#define LSTR 616     // LDS A row stride (608 + 8 pad): 2-way bank alias only

typedef __attribute__((ext_vector_type(8))) short short8;
typedef __attribute__((ext_vector_type(4))) float f32x4;

// workspace layout (bytes)
#define SZ_WF 17510400ull
#define OFF_WHH0 0ull
#define OFF_WIH1 17510400ull
#define OFF_WHH1 35020800ull
#define OFF_STATE 52531200ull
#define SZ_HF 307200ull              // 64*1200 fp32
#define SZ_HB 155648ull              // 64*1216 bf16
#define OFF_H0F (OFF_STATE)
#define OFF_H1F (OFF_STATE + 2ull*SZ_HF)
#define OFF_H0B (OFF_STATE + 4ull*SZ_HF)
#define OFF_H1B (OFF_H0B + 2ull*SZ_HB)
#define OFF_GX  (OFF_H1B + 2ull*SZ_HB)
#define SZ_GX 921600ull              // 64*3600 fp32
#define WS_NEEDED (OFF_GX + 2ull*SZ_GX)
#define STATE_U128 115712            // (4*SZ_HF + 4*SZ_HB)/16

__device__ __forceinline__ unsigned short f2bf(float f){
  unsigned u = __float_as_uint(f);
  unsigned r = u + 0x7FFFu + ((u >> 16) & 1u);
  return (unsigned short)(r >> 16);
}
__device__ __forceinline__ float bf2f(unsigned short s){
  return __uint_as_float(((unsigned)s) << 16);
}
__device__ __forceinline__ float sigmoid_f(float v){ return 1.f/(1.f + __expf(-v)); }
__device__ __forceinline__ float tanh_f(float v){ float e = __expf(2.f*v); return 1.f - 2.f/(e + 1.f); }

// Split W[3600][K=1200] fp32 -> bf16 hi/lo in MFMA B-fragment order.
__global__ void prep_w(const float* __restrict__ W, unsigned short* __restrict__ Wf){
  int blk = blockIdx.x;
  int nt = blk / KS_TOT, ks = blk - nt*KS_TOT;
  int l = threadIdx.x;
  int n = nt*16 + (l & 15);
  int k0 = ks*32 + (l >> 4)*8;
  alignas(16) unsigned short hi[8];
  alignas(16) unsigned short lo[8];
  #pragma unroll
  for (int j = 0; j < 8; j++){
    int k = k0 + j;
    float w = (k < Hh) ? W[(size_t)n*Hh + k] : 0.f;
    unsigned short h16 = f2bf(w);
    hi[j] = h16;
    lo[j] = f2bf(w - bf2f(h16));
  }
  size_t cbase = ((size_t)(nt*KS_TOT + ks))*1024ull;
  *(short8*)(Wf + cbase + (size_t)l*8)        = *(const short8*)hi;
  *(short8*)(Wf + cbase + 512 + (size_t)l*8)  = *(const short8*)lo;
}

__global__ void init_state(char* __restrict__ ws){
  size_t i = (size_t)blockIdx.x*256 + threadIdx.x;
  if (i < STATE_U128){
    f32x4 z = {0.f,0.f,0.f,0.f};
    ((f32x4*)(ws + OFF_STATE))[i] = z;
  }
}

// roles: bid/75 == 0 -> layer0 full step (t=s)
//                 1 -> layer1 input-side gx (t=s-1)
//                 2 -> layer1 h-side + fuse (t=s-2)
__global__ void __launch_bounds__(192) gru_step(
    char* __restrict__ ws,
    const float* __restrict__ x,
    const float* __restrict__ Wih0,
    const float* __restrict__ bih0, const float* __restrict__ bhh0,
    const float* __restrict__ bih1, const float* __restrict__ bhh1,
    int s)
{
  const int bid  = blockIdx.x;
  const int role = bid / NTG;
  const int nb   = bid - role*NTG;
  int t;
  if (role == 0){ if (s > TT-1) return;          t = s;     }
  else if (role == 1){ if (s < 1 || s > TT) return; t = s-1; }
  else {          if (s < 2) return;             t = s-2;   }
  const int par  = t & 1;
  const int wave = threadIdx.x >> 6;      // gate: 0=r 1=z 2=n
  const int lane = threadIdx.x & 63;
  const int col  = lane & 15;
  const int kg   = lane >> 4;

  const unsigned short* hbf_in;
  size_t woff;
  if (role == 0){ hbf_in = (const unsigned short*)(ws + OFF_H0B + (size_t)par*SZ_HB);      woff = OFF_WHH0; }
  else if (role == 1){ hbf_in = (const unsigned short*)(ws + OFF_H0B + (size_t)(s&1)*SZ_HB); woff = OFF_WIH1; }
  else { hbf_in = (const unsigned short*)(ws + OFF_H1B + (size_t)par*SZ_HB);               woff = OFF_WHH1; }

  __shared__ alignas(16) unsigned short hA[64][LSTR];
  __shared__ float xl[64][II];
  __shared__ float rz[2][64][17];

  // layer0: stage x[t] rows and per-lane W_ih0 row (exact fp32 input path)
  float wr[II];
  if (role == 0){
    for (int i = threadIdx.x; i < 64*II; i += 192){
      int r = i / II, c = i - r*II;
      xl[r][c] = x[((size_t)r*TT + t)*II + c];
    }
    const int wrow = wave*Hh + nb*16 + col;
    #pragma unroll
    for (int i = 0; i < II; i++) wr[i] = Wih0[(size_t)wrow*II + i];
  }

  f32x4 acc_hi[4], acc_lo[4];
  #pragma unroll
  for (int m = 0; m < 4; m++){
    acc_hi[m] = (f32x4){0.f,0.f,0.f,0.f};
    acc_lo[m] = (f32x4){0.f,0.f,0.f,0.f};
  }
  const int ntW = wave*NTG + nb;

  for (int ch = 0; ch < 2; ch++){
    __syncthreads();
    // stage A: [64][608] bf16 slice of state (coalesced 16B per thread)
    for (int i = threadIdx.x; i < 64*(KCH/8); i += 192){
      int r = i / (KCH/8), c8 = i - r*(KCH/8);
      *(short8*)&hA[r][c8*8] =
        *(const short8*)&hbf_in[(size_t)r*HP + ch*KCH + c8*8];
    }
    __syncthreads();

    const short8* wb = (const short8*)(ws + woff)
                     + ((size_t)(ntW*KS_TOT + ch*KS_HALF))*128 + lane;
    #pragma unroll
    for (int ksl = 0; ksl < KS_HALF; ksl++){
      short8 whi = wb[ksl*128];
      short8 wlo = wb[ksl*128 + 64];
      #pragma unroll
      for (int mt = 0; mt < 4; mt++){
        short8 a = *(const short8*)&hA[mt*16 + col][ksl*32 + kg*8];
        acc_hi[mt] = __builtin_amdgcn_mfma_f32_16x16x32_bf16(a, whi, acc_hi[mt], 0, 0, 0);
        acc_lo[mt] = __builtin_amdgcn_mfma_f32_16x16x32_bf16(a, wlo, acc_lo[mt], 0, 0, 0);
      }
    }
  }

  const int gidx = wave*Hh + nb*16 + col;
  const int hcol = nb*16 + col;

  if (role == 1){
    // store gx1[t] = W_ih1 . out0[t] + bih1  (fp32)
    const float bI = bih1[gidx];
    float* gxo = (float*)(ws + OFF_GX + (size_t)(t&1)*SZ_GX);
    #pragma unroll
    for (int mt = 0; mt < 4; mt++){
      #pragma unroll
      for (int j = 0; j < 4; j++){
        int row = mt*16 + kg*4 + j;
        gxo[(size_t)row*3600 + gidx] = acc_hi[mt][j] + acc_lo[mt][j] + bI;
      }
    }
    return;
  }

  // roles 0 and 2: full gate fusion
  f32x4 gh[4];
  #pragma unroll
  for (int mt = 0; mt < 4; mt++) gh[mt] = acc_hi[mt] + acc_lo[mt];

  float gx[4][4];
  float bI, bH;
  if (role == 0){
    bI = bih0[gidx]; bH = bhh0[gidx];
    #pragma unroll
    for (int mt = 0; mt < 4; mt++){
      #pragma unroll
      for (int j = 0; j < 4; j++){
        const float* xr = xl[mt*16 + kg*4 + j];
        float sacc = 0.f;
        #pragma unroll
        for (int i = 0; i < II; i++) sacc += wr[i]*xr[i];
        gx[mt][j] = sacc + bI;          // fold bih0 here
      }
    }
    bI = 0.f;  // already folded
  } else {
    bH = bhh1[gidx];
    const float* gxi = (const float*)(ws + OFF_GX + (size_t)par*SZ_GX);
    #pragma unroll
    for (int mt = 0; mt < 4; mt++){
      #pragma unroll
      for (int j = 0; j < 4; j++){
        int row = mt*16 + kg*4 + j;
        gx[mt][j] = gxi[(size_t)row*3600 + gidx];   // includes bih1
      }
    }
    bI = 0.f;
  }

  if (wave < 2){
    #pragma unroll
    for (int mt = 0; mt < 4; mt++){
      #pragma unroll
      for (int j = 0; j < 4; j++){
        int row = mt*16 + kg*4 + j;
        rz[wave][row][col] = sigmoid_f(gh[mt][j] + gx[mt][j] + bH);
      }
    }
  }
  __syncthreads();
  if (wave == 2){
    const size_t fbase = (role == 0) ? OFF_H0F : OFF_H1F;
    const size_t bbase = (role == 0) ? OFF_H0B : OFF_H1B;
    const float* hf_in  = (const float*)(ws + fbase + (size_t)par*SZ_HF);
    float*       hf_out = (float*)      (ws + fbase + (size_t)(par^1)*SZ_HF);
    unsigned short* hb_out = (unsigned short*)(ws + bbase + (size_t)(par^1)*SZ_HB);
    #pragma unroll
    for (int mt = 0; mt < 4; mt++){
      #pragma unroll
      for (int j = 0; j < 4; j++){
        int row = mt*16 + kg*4 + j;     // batch index b
        float rg = rz[0][row][col];
        float zg = rz[1][row][col];
        float ng = tanh_f(gx[mt][j] + rg*(gh[mt][j] + bH));
        float hold = hf_in[(size_t)row*Hh + hcol];
        float hn = (1.f - zg)*ng + zg*hold;
        hf_out[(size_t)row*Hh + hcol] = hn;
        hb_out[(size_t)row*HP + hcol] = f2bf(hn);
      }
    }
  }
}

__global__ void write_out(const char* __restrict__ ws, float* __restrict__ out){
  int i = blockIdx.x*256 + threadIdx.x;
  if (i < 76800)        out[i] = *(const float*)(ws + OFF_H0F + (size_t)i*4);
  else if (i < 153600)  out[i] = *(const float*)(ws + OFF_H1F + (size_t)(i - 76800)*4);
}

extern "C" void kernel_launch(void* const* d_in, const int* in_sizes, int n_in,
                              void* d_out, int out_size, void* d_ws, size_t ws_size,
                              hipStream_t stream)
{
  const float* x    = (const float*)d_in[0];
  const float* Wih0 = (const float*)d_in[1];
  const float* Whh0 = (const float*)d_in[2];
  const float* bih0 = (const float*)d_in[3];
  const float* bhh0 = (const float*)d_in[4];
  const float* Wih1 = (const float*)d_in[5];
  const float* Whh1 = (const float*)d_in[6];
  const float* bih1 = (const float*)d_in[7];
  const float* bhh1 = (const float*)d_in[8];
  char* ws = (char*)d_ws;
  if (ws_size < WS_NEEDED) return;   // need ~53.6 MiB scratch

  dim3 pgrid(225*KS_TOT);
  prep_w<<<pgrid, 64, 0, stream>>>(Whh0, (unsigned short*)(ws + OFF_WHH0));
  prep_w<<<pgrid, 64, 0, stream>>>(Wih1, (unsigned short*)(ws + OFF_WIH1));
  prep_w<<<pgrid, 64, 0, stream>>>(Whh1, (unsigned short*)(ws + OFF_WHH1));
  init_state<<<452, 256, 0, stream>>>(ws);

  for (int s = 0; s < TT + 2; s++)
    gru_step<<<3*NTG, 192, 0, stream>>>(ws, x, Wih0, bih0, bhh0, bih1, bhh1, s);

  write_out<<<600, 256, 0, stream>>>(ws, (float*)d_out);
}

// Round 4
// 10059.912 us; speedup vs baseline: 1.9851x; 1.8402x over previous
//
#include <hip/hip_runtime.h>
#include <hip/hip_bf16.h>

// ---------------------------------------------------------------------------
// 2-layer GRU, H=1200, B=64, T=512, I=30. Output = [h_last_l0, h_last_l1].
// R3': ONE persistent kernel, 225 blocks x 512 threads, 1 block/CU (forced by
// 124KB LDS). All split-bf16 weights live in VGPRs (120/lane). Single-level
// device-scope grid barrier per step (514 barriers). Roles:
//   role0 = layer0 step t=s (W_hh0), role1 = gx1 t=s-1 (W_ih1),
//   role2 = layer1 fuse t=s-2 (W_hh1).
// ---------------------------------------------------------------------------

#define Hh 1200
#define HP 1280          // state row width (bf16 elems); cols >=1200 stay 0
#define TT 512
#define II 30
#define KS_TOT 38        // frag-table K units (38*32 = 1216)
#define KS_PW 5          // K units per wave (8 waves cover 40; pad = zeros)
#define NTG 75
#define NBLK 225
#define NTHR 512

typedef __attribute__((ext_vector_type(8))) short short8;
typedef __attribute__((ext_vector_type(4))) float f32x4;

// workspace layout (bytes)
#define SZ_WF 17510400ull            // per matrix: 225*38*1024 elems * 2B
#define OFF_WHH0 0ull
#define OFF_WIH1 SZ_WF
#define OFF_WHH1 (2ull*SZ_WF)
#define OFF_STATE (3ull*SZ_WF)       // 52,531,200
#define SZ_HF 307200ull              // 64*1200 fp32
#define SZ_HB 163840ull              // 64*1280 bf16
#define OFF_H0F OFF_STATE
#define OFF_H1F (OFF_H0F + 2ull*SZ_HF)
#define OFF_H0B (OFF_H1F + 2ull*SZ_HF)
#define OFF_H1B (OFF_H0B + 2ull*SZ_HB)
#define OFF_GX  (OFF_H1B + 2ull*SZ_HB)
#define SZ_GX 921600ull              // 64*3600 fp32
#define OFF_BAR (OFF_GX + 2ull*SZ_GX)
#define WS_NEEDED (OFF_BAR + 16384ull)
#define STATE_BYTES (4ull*SZ_HF + 4ull*SZ_HB)   // 1,884,160

__device__ __forceinline__ unsigned short f2bf(float f){
  unsigned u = __float_as_uint(f);
  unsigned r = u + 0x7FFFu + ((u >> 16) & 1u);
  return (unsigned short)(r >> 16);
}
__device__ __forceinline__ float bf2f(unsigned short s){
  return __uint_as_float(((unsigned)s) << 16);
}
__device__ __forceinline__ float sigmoid_f(float v){ return 1.f/(1.f + __expf(-v)); }
__device__ __forceinline__ float tanh_f(float v){ float e = __expf(2.f*v); return 1.f - 2.f/(e + 1.f); }

// Split W[3600][K<=1200] fp32 -> bf16 hi/lo in MFMA B-fragment order.
// chunk (nt,ks): lane l, split sp holds W[nt*16+(l&15)][ks*32+(l>>4)*8+0..7]
__global__ void prep_w(const float* __restrict__ W, unsigned short* __restrict__ Wf){
  int blk = blockIdx.x;
  int nt = blk / KS_TOT, ks = blk - nt*KS_TOT;
  int l = threadIdx.x;
  int n = nt*16 + (l & 15);
  int k0 = ks*32 + (l >> 4)*8;
  alignas(16) unsigned short hi[8];
  alignas(16) unsigned short lo[8];
  #pragma unroll
  for (int j = 0; j < 8; j++){
    int k = k0 + j;
    float w = (k < Hh) ? W[(size_t)n*Hh + k] : 0.f;
    unsigned short h16 = f2bf(w);
    hi[j] = h16;
    lo[j] = f2bf(w - bf2f(h16));
  }
  size_t cbase = ((size_t)(nt*KS_TOT + ks))*1024ull;
  *(short8*)(Wf + cbase + (size_t)l*8)        = *(const short8*)hi;
  *(short8*)(Wf + cbase + 512 + (size_t)l*8)  = *(const short8*)lo;
}

__global__ void init_state(char* __restrict__ ws){
  size_t i = (size_t)blockIdx.x*256 + threadIdx.x;
  size_t n_state = STATE_BYTES/16;                 // 117,760 16B units
  if (i < n_state){
    f32x4 z = {0.f,0.f,0.f,0.f};
    ((f32x4*)(ws + OFF_STATE))[i] = z;
  }
  if (i < 1024){
    ((f32x4*)(ws + OFF_BAR))[i] = (f32x4){0.f,0.f,0.f,0.f};
  }
}

__global__ void __launch_bounds__(NTHR, 2) gru_persist(
    char* __restrict__ ws,
    const float* __restrict__ x,
    const float* __restrict__ Wih0,
    const float* __restrict__ bih0, const float* __restrict__ bhh0,
    const float* __restrict__ bih1, const float* __restrict__ bhh1)
{
  const int bid  = blockIdx.x;
  const int role = bid / NTG;
  const int nb   = bid - role*NTG;
  const int tid  = threadIdx.x;
  const int wv   = tid >> 6;
  const int lane = tid & 63;
  const int col  = lane & 15;
  const int kg   = lane >> 4;
  const int ks0  = wv * KS_PW;
  const int ec   = tid & 15;            // epilogue column-in-tile
  const int bq   = tid >> 4;            // epilogue batch slot (0..31)
  const int nce  = nb*16 + ec;          // global column

  __shared__ float part[12][8][256];    // 96 KB split-K partials
  __shared__ float red[12][256];        // 12 KB reduced tiles
  __shared__ float xl[64][II];          // role0: x[t]
  __shared__ float wl[48][II];          // role0: W_ih0 slice

  int* bar_flags = (int*)(ws + OFF_BAR);          // 64B stride per block

  // ---- resident weights: 3 gates x 5 ks x {hi,lo} = 30 short8 = 120 VGPRs
  const short8* wt = (const short8*)(ws + ((role==0)?OFF_WHH0:(role==1)?OFF_WIH1:OFF_WHH1));
  short8 wfr[3][KS_PW][2];
  #pragma unroll
  for (int g = 0; g < 3; g++)
    #pragma unroll
    for (int k = 0; k < KS_PW; k++){
      int ks = ks0 + k;
      #pragma unroll
      for (int sp = 0; sp < 2; sp++){
        short8 v = {0,0,0,0,0,0,0,0};
        if (ks < KS_TOT)
          v = wt[((size_t)((g*NTG + nb)*KS_TOT + ks))*128 + sp*64 + lane];
        wfr[g][k][sp] = v;
      }
    }

  // role0: stage W_ih0 slice (3 gates x 16 cols x 30) into LDS once
  if (role == 0){
    for (int i = tid; i < 48*II; i += NTHR){
      int rl = i/II, c = i - rl*II;
      int g = rl >> 4, cl = rl & 15;
      wl[rl][c] = Wih0[(size_t)(g*Hh + nb*16 + cl)*II + c];
    }
  }

  // per-thread epilogue biases
  float bA0=0.f,bA1=0.f,bA2=0.f, bB0=0.f,bB1=0.f,bB2=0.f;
  if (role == 0){
    bA0 = bih0[nce]; bA1 = bih0[Hh+nce]; bA2 = bih0[2*Hh+nce];
    bB0 = bhh0[nce]; bB1 = bhh0[Hh+nce]; bB2 = bhh0[2*Hh+nce];
  } else if (role == 1){
    bA0 = bih1[nce]; bA1 = bih1[Hh+nce]; bA2 = bih1[2*Hh+nce];
  } else {
    bB0 = bhh1[nce]; bB1 = bhh1[Hh+nce]; bB2 = bhh1[2*Hh+nce];
  }

  for (int s = 0; s < TT + 2; s++){
    const bool active = (role==0) ? (s < TT) : (role==1) ? (s >= 1 && s <= TT) : (s >= 2);
    const int t   = s - role;
    const int par = t & 1;

    if (active){
      const unsigned short* Ab;
      if (role == 0)      Ab = (const unsigned short*)(ws + OFF_H0B + (size_t)par*SZ_HB);
      else if (role == 1) Ab = (const unsigned short*)(ws + OFF_H0B + (size_t)((t+1)&1)*SZ_HB);
      else                Ab = (const unsigned short*)(ws + OFF_H1B + (size_t)par*SZ_HB);

      if (role == 0){
        for (int i = tid; i < 64*II; i += NTHR){
          int b = i/II, c = i - b*II;
          xl[b][c] = x[(size_t)b*(TT*II) + t*II + c];
        }
      }

      f32x4 acc[3][4];
      #pragma unroll
      for (int g = 0; g < 3; g++)
        #pragma unroll
        for (int m = 0; m < 4; m++) acc[g][m] = (f32x4){0.f,0.f,0.f,0.f};

      #pragma unroll
      for (int k = 0; k < KS_PW; k++){
        short8 a[4];
        #pragma unroll
        for (int m = 0; m < 4; m++)
          a[m] = *(const short8*)&Ab[(size_t)(m*16 + col)*HP + (ks0 + k)*32 + kg*8];
        #pragma unroll
        for (int g = 0; g < 3; g++)
          #pragma unroll
          for (int m = 0; m < 4; m++){
            acc[g][m] = __builtin_amdgcn_mfma_f32_16x16x32_bf16(a[m], wfr[g][k][0], acc[g][m], 0,0,0);
            acc[g][m] = __builtin_amdgcn_mfma_f32_16x16x32_bf16(a[m], wfr[g][k][1], acc[g][m], 0,0,0);
          }
      }
      #pragma unroll
      for (int g = 0; g < 3; g++)
        #pragma unroll
        for (int m = 0; m < 4; m++)
          *(f32x4*)&part[g*4 + m][wv][lane*4] = acc[g][m];
    }
    __syncthreads();

    if (active){
      // split-K reduce: 12 tiles x 256 elems, 8 partials each
      #pragma unroll
      for (int r = 0; r < 6; r++){
        int o = r*NTHR + tid;
        int tile = o >> 8, e = o & 255;
        float v = part[tile][0][e] + part[tile][1][e] + part[tile][2][e] + part[tile][3][e]
                + part[tile][4][e] + part[tile][5][e] + part[tile][6][e] + part[tile][7][e];
        red[tile][e] = v;
      }
    }
    __syncthreads();

    if (active){
      if (role == 1){
        float* gxo = (float*)(ws + OFF_GX + (size_t)par*SZ_GX);
        #pragma unroll
        for (int h = 0; h < 2; h++){
          int b = bq + h*32;
          int mt = b >> 4, dr = b & 15;
          int e = ((dr>>2)<<6) | (ec<<2) | (dr&3);
          gxo[(size_t)b*3600 +          nce] = red[mt][e]     + bA0;
          gxo[(size_t)b*3600 + Hh   +   nce] = red[4+mt][e]   + bA1;
          gxo[(size_t)b*3600 + 2*Hh +   nce] = red[8+mt][e]   + bA2;
        }
      } else {
        const size_t ffo = (role == 0) ? OFF_H0F : OFF_H1F;
        const size_t bbo = (role == 0) ? OFF_H0B : OFF_H1B;
        const float* hin = (const float*)(ws + ffo + (size_t)par*SZ_HF);
        float* hout      = (float*)      (ws + ffo + (size_t)(par^1)*SZ_HF);
        unsigned short* hbout = (unsigned short*)(ws + bbo + (size_t)(par^1)*SZ_HB);
        const float* gxi = (const float*)(ws + OFF_GX + (size_t)par*SZ_GX);
        #pragma unroll
        for (int h = 0; h < 2; h++){
          int b = bq + h*32;
          int mt = b >> 4, dr = b & 15;
          int e = ((dr>>2)<<6) | (ec<<2) | (dr&3);
          float g0, g1, g2;
          if (role == 0){
            float s0 = bA0, s1 = bA1, s2 = bA2;
            #pragma unroll
            for (int c = 0; c < II; c++){
              float xv = xl[b][c];
              s0 += wl[ec][c]      * xv;
              s1 += wl[16+ec][c]   * xv;
              s2 += wl[32+ec][c]   * xv;
            }
            g0 = s0; g1 = s1; g2 = s2;
          } else {
            g0 = gxi[(size_t)b*3600 +        nce];
            g1 = gxi[(size_t)b*3600 + Hh   + nce];
            g2 = gxi[(size_t)b*3600 + 2*Hh + nce];
          }
          float rr = sigmoid_f(red[mt][e]   + g0 + bB0);
          float zz = sigmoid_f(red[4+mt][e] + g1 + bB1);
          float nn = tanh_f(g2 + rr*(red[8+mt][e] + bB2));
          float hold = hin[(size_t)b*Hh + nce];
          float hn = (1.f - zz)*nn + zz*hold;
          hout[(size_t)b*Hh + nce] = hn;
          hbout[(size_t)b*HP + nce] = f2bf(hn);
        }
      }
    }

    // -------- single-level grid barrier (generation = s+1) --------
    __syncthreads();                       // all waves drained their stores
    if (tid == 0){
      __builtin_amdgcn_fence(__ATOMIC_RELEASE, "agent");   // L2 writeback
      __hip_atomic_store(&bar_flags[bid*16], s+1, __ATOMIC_RELAXED, __HIP_MEMORY_SCOPE_AGENT);
    }
    if (tid < NBLK){
      while (__hip_atomic_load(&bar_flags[tid*16], __ATOMIC_RELAXED, __HIP_MEMORY_SCOPE_AGENT) < s+1)
        __builtin_amdgcn_s_sleep(1);
    }
    __syncthreads();
    if (tid == 0)
      __builtin_amdgcn_fence(__ATOMIC_ACQUIRE, "agent");   // L1/L2 invalidate
    __syncthreads();
  }
}

__global__ void write_out(const char* __restrict__ ws, float* __restrict__ out){
  int i = blockIdx.x*256 + threadIdx.x;
  if (i < 76800)        out[i] = *(const float*)(ws + OFF_H0F + (size_t)i*4);
  else if (i < 153600)  out[i] = *(const float*)(ws + OFF_H1F + (size_t)(i - 76800)*4);
}

extern "C" void kernel_launch(void* const* d_in, const int* in_sizes, int n_in,
                              void* d_out, int out_size, void* d_ws, size_t ws_size,
                              hipStream_t stream)
{
  const float* x    = (const float*)d_in[0];
  const float* Wih0 = (const float*)d_in[1];
  const float* Whh0 = (const float*)d_in[2];
  const float* bih0 = (const float*)d_in[3];
  const float* bhh0 = (const float*)d_in[4];
  const float* Wih1 = (const float*)d_in[5];
  const float* Whh1 = (const float*)d_in[6];
  const float* bih1 = (const float*)d_in[7];
  const float* bhh1 = (const float*)d_in[8];
  char* ws = (char*)d_ws;
  if (ws_size < WS_NEEDED) return;   // ~56.3 MB scratch

  dim3 pgrid(NBLK*KS_TOT);
  prep_w<<<pgrid, 64, 0, stream>>>(Whh0, (unsigned short*)(ws + OFF_WHH0));
  prep_w<<<pgrid, 64, 0, stream>>>(Wih1, (unsigned short*)(ws + OFF_WIH1));
  prep_w<<<pgrid, 64, 0, stream>>>(Whh1, (unsigned short*)(ws + OFF_WHH1));
  init_state<<<512, 256, 0, stream>>>(ws);

  gru_persist<<<NBLK, NTHR, 0, stream>>>(ws, x, Wih0, bih0, bhh0, bih1, bhh1);

  write_out<<<600, 256, 0, stream>>>(ws, (float*)d_out);
}

// Round 5
// 7592.113 us; speedup vs baseline: 2.6304x; 1.3250x over previous
//
#include <hip/hip_runtime.h>
#include <hip/hip_bf16.h>

// ---------------------------------------------------------------------------
// 2-layer GRU, H=1200, B=64, T=512, I=30. Output = [h_last_l0, h_last_l1].
// R5: persistent kernel (225 blocks x 512 thr, 1 block/CU via 128KB LDS).
//  - amdgpu_waves_per_eu(2,2): unlock 256-VGPR budget -> split-bf16 weights
//    truly VGPR/AGPR-resident (R4 counter showed 128 VGPR = spilled).
//  - cross-block state stores are agent-scope relaxed atomics (write-through,
//    L2-clean) -> release fence wbl2 has nothing to push to HBM.
//  - block-private fp32 h state lives in LDS; dumped to ws at last step.
//  - grid barrier identical to R3' (proven): flags + agent fences.
// Roles: role0 = layer0 step t=s (W_hh0), role1 = gx1 t=s-1 (W_ih1),
//        role2 = layer1 fuse t=s-2 (W_hh1).
// ---------------------------------------------------------------------------

#define Hh 1200
#define HP 1280          // bf16 state row stride; cols >=1200 stay 0
#define TT 512
#define II 30
#define KS_TOT 38        // 38*32 = 1216 >= 1200
#define KS_PW 5          // 8 waves x 5 = 40 k-units (2 zero-padded)
#define NTG 75
#define NBLK 225
#define NTHR 512

typedef __attribute__((ext_vector_type(8))) short short8;
typedef __attribute__((ext_vector_type(4))) float f32x4;

// workspace layout (bytes)
#define SZ_WF 17510400ull            // per matrix: 225*38*1024 elems * 2B
#define OFF_WHH0 0ull
#define OFF_WIH1 SZ_WF
#define OFF_WHH1 (2ull*SZ_WF)
#define OFF_STATE (3ull*SZ_WF)       // 52,531,200
#define SZ_HF 307200ull              // 64*1200 fp32 (final dump, single)
#define SZ_HB 163840ull              // 64*1280 bf16
#define SZ_GX 921600ull              // 64*3600 fp32
#define OFF_H0F OFF_STATE
#define OFF_H1F (OFF_H0F + SZ_HF)
#define OFF_H0B (OFF_H1F + SZ_HF)
#define OFF_H1B (OFF_H0B + 2ull*SZ_HB)
#define OFF_GX  (OFF_H1B + 2ull*SZ_HB)
#define STATE_BYTES (2ull*SZ_HF + 4ull*SZ_HB + 2ull*SZ_GX)   // 3,112,960
#define OFF_BAR (OFF_STATE + STATE_BYTES)
#define WS_NEEDED (OFF_BAR + 16384ull)

__device__ __forceinline__ unsigned short f2bf(float f){
  unsigned u = __float_as_uint(f);
  unsigned r = u + 0x7FFFu + ((u >> 16) & 1u);   // RNE
  return (unsigned short)(r >> 16);
}
__device__ __forceinline__ float bf2f(unsigned short s){
  return __uint_as_float(((unsigned)s) << 16);
}
__device__ __forceinline__ float sigmoid_f(float v){ return 1.f/(1.f + __expf(-v)); }
__device__ __forceinline__ float tanh_f(float v){ float e = __expf(2.f*v); return 1.f - 2.f/(e + 1.f); }
__device__ __forceinline__ unsigned long long pack2f(float a, float b){
  union { float f[2]; unsigned long long u; } v; v.f[0]=a; v.f[1]=b; return v.u;
}

// Split W[3600][K<=1200] fp32 -> bf16 hi/lo in MFMA B-fragment order.
__global__ void prep_w(const float* __restrict__ W, unsigned short* __restrict__ Wf){
  int blk = blockIdx.x;
  int nt = blk / KS_TOT, ks = blk - nt*KS_TOT;
  int l = threadIdx.x;
  int n = nt*16 + (l & 15);
  int k0 = ks*32 + (l >> 4)*8;
  alignas(16) unsigned short hi[8];
  alignas(16) unsigned short lo[8];
  #pragma unroll
  for (int j = 0; j < 8; j++){
    int k = k0 + j;
    float w = (k < Hh) ? W[(size_t)n*Hh + k] : 0.f;
    unsigned short h16 = f2bf(w);
    hi[j] = h16;
    lo[j] = f2bf(w - bf2f(h16));
  }
  size_t cbase = ((size_t)(nt*KS_TOT + ks))*1024ull;
  *(short8*)(Wf + cbase + (size_t)l*8)        = *(const short8*)hi;
  *(short8*)(Wf + cbase + 512 + (size_t)l*8)  = *(const short8*)lo;
}

__global__ void init_state(char* __restrict__ ws){
  size_t i = (size_t)blockIdx.x*256 + threadIdx.x;
  size_t n_all = (STATE_BYTES + 16384ull)/16ull;   // state + barrier flags
  if (i < n_all){
    f32x4 z = {0.f,0.f,0.f,0.f};
    ((f32x4*)(ws + OFF_STATE))[i] = z;
  }
}

__global__ void __launch_bounds__(NTHR)
__attribute__((amdgpu_waves_per_eu(2, 2)))
gru_persist(
    char* __restrict__ ws,
    const float* __restrict__ x,
    const float* __restrict__ Wih0,
    const float* __restrict__ bih0, const float* __restrict__ bhh0,
    const float* __restrict__ bih1, const float* __restrict__ bhh1)
{
  const int bid  = blockIdx.x;
  const int role = bid / NTG;
  const int nb   = bid - role*NTG;
  const int tid  = threadIdx.x;
  const int wv   = tid >> 6;
  const int lane = tid & 63;
  const int col  = lane & 15;
  const int kg   = lane >> 4;
  const int ks0  = wv * KS_PW;
  // epilogue mapping: thread -> (batch, column-pair)
  const int eb  = tid >> 3;            // 0..63
  const int ecp = tid & 7;             // col pair 0..7
  const int c0  = ecp*2;
  const int gc0 = nb*16 + c0;          // global column (even)
  const int lastS = (role == 0) ? (TT-1) : (TT+1);

  __shared__ float part[12][8][256];   // 96 KB split-K partials
  __shared__ float red[12][256];       // 12 KB reduced tiles
  __shared__ float xl[64][II];         // role0: x[t]
  __shared__ float wl[48][II];         // role0: W_ih0 slice
  __shared__ float hfl[64][16];        // block-private fp32 h columns

  int* bar_flags = (int*)(ws + OFF_BAR);   // 64B stride per block

  // zero private h state
  for (int i = tid; i < 64*16; i += NTHR) ((float*)hfl)[i] = 0.f;

  // ---- resident weights: 3 gates x 5 ks x {hi,lo} = 30 short8 = 120 regs
  const short8* wt = (const short8*)(ws + ((role==0)?OFF_WHH0:(role==1)?OFF_WIH1:OFF_WHH1));
  short8 wfr[3][KS_PW][2];
  #pragma unroll
  for (int g = 0; g < 3; g++)
    #pragma unroll
    for (int k = 0; k < KS_PW; k++){
      int ks = ks0 + k;
      #pragma unroll
      for (int sp = 0; sp < 2; sp++){
        short8 v = {0,0,0,0,0,0,0,0};
        if (ks < KS_TOT)
          v = wt[((size_t)((g*NTG + nb)*KS_TOT + ks))*128 + sp*64 + lane];
        wfr[g][k][sp] = v;
      }
    }

  // role0: stage W_ih0 slice (3 gates x 16 cols x 30) into LDS once
  if (role == 0){
    for (int i = tid; i < 48*II; i += NTHR){
      int rl = i/II, c = i - rl*II;
      int g = rl >> 4, cl = rl & 15;
      wl[rl][c] = Wih0[(size_t)(g*Hh + nb*16 + cl)*II + c];
    }
  }

  // per-thread epilogue biases (2 columns each)
  float bIv[3][2] = {{0.f,0.f},{0.f,0.f},{0.f,0.f}};
  float bHv[3][2] = {{0.f,0.f},{0.f,0.f},{0.f,0.f}};
  if (role == 0){
    #pragma unroll
    for (int g = 0; g < 3; g++){
      bIv[g][0] = bih0[g*Hh + gc0]; bIv[g][1] = bih0[g*Hh + gc0 + 1];
      bHv[g][0] = bhh0[g*Hh + gc0]; bHv[g][1] = bhh0[g*Hh + gc0 + 1];
    }
  } else if (role == 1){
    #pragma unroll
    for (int g = 0; g < 3; g++){
      bIv[g][0] = bih1[g*Hh + gc0]; bIv[g][1] = bih1[g*Hh + gc0 + 1];
    }
  } else {
    #pragma unroll
    for (int g = 0; g < 3; g++){
      bHv[g][0] = bhh1[g*Hh + gc0]; bHv[g][1] = bhh1[g*Hh + gc0 + 1];
    }
  }

  for (int s = 0; s < TT + 2; s++){
    const bool active = (role==0) ? (s < TT) : (role==1) ? (s >= 1 && s <= TT) : (s >= 2);
    const int t   = s - role;
    const int par = t & 1;

    if (active){
      const unsigned short* Ab;
      if (role == 0)      Ab = (const unsigned short*)(ws + OFF_H0B + (size_t)par*SZ_HB);
      else if (role == 1) Ab = (const unsigned short*)(ws + OFF_H0B + (size_t)((t+1)&1)*SZ_HB);
      else                Ab = (const unsigned short*)(ws + OFF_H1B + (size_t)par*SZ_HB);

      if (role == 0){
        for (int i = tid; i < 64*II; i += NTHR){
          int b = i/II, c = i - b*II;
          xl[b][c] = x[(size_t)b*(TT*II) + t*II + c];
        }
      }

      f32x4 acc[3][4];
      #pragma unroll
      for (int g = 0; g < 3; g++)
        #pragma unroll
        for (int m = 0; m < 4; m++) acc[g][m] = (f32x4){0.f,0.f,0.f,0.f};

      #pragma unroll
      for (int k = 0; k < KS_PW; k++){
        short8 a[4];
        #pragma unroll
        for (int m = 0; m < 4; m++)
          a[m] = *(const short8*)&Ab[(size_t)(m*16 + col)*HP + (ks0 + k)*32 + kg*8];
        #pragma unroll
        for (int g = 0; g < 3; g++)
          #pragma unroll
          for (int m = 0; m < 4; m++){
            acc[g][m] = __builtin_amdgcn_mfma_f32_16x16x32_bf16(a[m], wfr[g][k][0], acc[g][m], 0,0,0);
            acc[g][m] = __builtin_amdgcn_mfma_f32_16x16x32_bf16(a[m], wfr[g][k][1], acc[g][m], 0,0,0);
          }
      }
      #pragma unroll
      for (int g = 0; g < 3; g++)
        #pragma unroll
        for (int m = 0; m < 4; m++)
          *(f32x4*)&part[g*4 + m][wv][lane*4] = acc[g][m];
    }
    __syncthreads();

    if (active){
      #pragma unroll
      for (int r = 0; r < 6; r++){
        int o = r*NTHR + tid;
        int tile = o >> 8, e = o & 255;
        float v = part[tile][0][e] + part[tile][1][e] + part[tile][2][e] + part[tile][3][e]
                + part[tile][4][e] + part[tile][5][e] + part[tile][6][e] + part[tile][7][e];
        red[tile][e] = v;
      }
    }
    __syncthreads();

    if (active){
      const int mt = eb >> 4, dr = eb & 15;
      const int e0 = ((dr>>2)<<6) | (c0<<2) | (dr&3);   // C-frag index, col c0
      if (role == 1){
        float* gxo = (float*)(ws + OFF_GX + (size_t)par*SZ_GX);
        #pragma unroll
        for (int g = 0; g < 3; g++){
          float v0 = red[g*4+mt][e0]     + bIv[g][0];
          float v1 = red[g*4+mt][e0 + 4] + bIv[g][1];
          __hip_atomic_store((unsigned long long*)&gxo[(size_t)eb*3600 + g*Hh + gc0],
                             pack2f(v0, v1), __ATOMIC_RELAXED, __HIP_MEMORY_SCOPE_AGENT);
        }
      } else {
        float gxv[3][2];
        if (role == 0){
          #pragma unroll
          for (int g = 0; g < 3; g++)
            #pragma unroll
            for (int j = 0; j < 2; j++){
              float sum = bIv[g][j];
              #pragma unroll
              for (int i = 0; i < II; i++) sum += wl[g*16 + c0 + j][i] * xl[eb][i];
              gxv[g][j] = sum;
            }
        } else {
          const float* gxi = (const float*)(ws + OFF_GX + (size_t)par*SZ_GX);
          #pragma unroll
          for (int g = 0; g < 3; g++)
            #pragma unroll
            for (int j = 0; j < 2; j++)
              gxv[g][j] = gxi[(size_t)eb*3600 + g*Hh + gc0 + j];
        }
        unsigned short* hbout = (unsigned short*)(ws + ((role==0)?OFF_H0B:OFF_H1B)
                                                   + (size_t)(par^1)*SZ_HB);
        float hq[2];
        unsigned short hb[2];
        #pragma unroll
        for (int j = 0; j < 2; j++){
          int e = e0 + j*4;
          float rr = sigmoid_f(red[mt][e]     + gxv[0][j] + bHv[0][j]);
          float zz = sigmoid_f(red[4+mt][e]   + gxv[1][j] + bHv[1][j]);
          float nn = tanh_f(gxv[2][j] + rr*(red[8+mt][e] + bHv[2][j]));
          float hold = hfl[eb][c0 + j];
          float hn = (1.f - zz)*nn + zz*hold;
          hfl[eb][c0 + j] = hn;
          hq[j] = hn;
          hb[j] = f2bf(hn);
        }
        unsigned pk = (unsigned)hb[0] | ((unsigned)hb[1] << 16);
        __hip_atomic_store((unsigned*)&hbout[(size_t)eb*HP + gc0], pk,
                           __ATOMIC_RELAXED, __HIP_MEMORY_SCOPE_AGENT);
        if (s == lastS){
          float* hfin = (float*)(ws + ((role==0)?OFF_H0F:OFF_H1F));
          hfin[(size_t)eb*Hh + gc0]     = hq[0];
          hfin[(size_t)eb*Hh + gc0 + 1] = hq[1];
        }
      }
    }

    // -------- grid barrier (generation = s+1), structure proven in R3' ----
    __syncthreads();                       // all waves' stores drained
    if (tid == 0){
      __builtin_amdgcn_fence(__ATOMIC_RELEASE, "agent");
      __hip_atomic_store(&bar_flags[bid*16], s+1, __ATOMIC_RELAXED, __HIP_MEMORY_SCOPE_AGENT);
    }
    if (tid < NBLK){
      while (__hip_atomic_load(&bar_flags[tid*16], __ATOMIC_RELAXED, __HIP_MEMORY_SCOPE_AGENT) < s+1)
        __builtin_amdgcn_s_sleep(1);
    }
    __syncthreads();
    if (tid == 0)
      __builtin_amdgcn_fence(__ATOMIC_ACQUIRE, "agent");   // L1/L2 invalidate
    __syncthreads();
  }
}

__global__ void write_out(const char* __restrict__ ws, float* __restrict__ out){
  int i = blockIdx.x*256 + threadIdx.x;
  if (i < 76800)        out[i] = *(const float*)(ws + OFF_H0F + (size_t)i*4);
  else if (i < 153600)  out[i] = *(const float*)(ws + OFF_H1F + (size_t)(i - 76800)*4);
}

extern "C" void kernel_launch(void* const* d_in, const int* in_sizes, int n_in,
                              void* d_out, int out_size, void* d_ws, size_t ws_size,
                              hipStream_t stream)
{
  const float* x    = (const float*)d_in[0];
  const float* Wih0 = (const float*)d_in[1];
  const float* Whh0 = (const float*)d_in[2];
  const float* bih0 = (const float*)d_in[3];
  const float* bhh0 = (const float*)d_in[4];
  const float* Wih1 = (const float*)d_in[5];
  const float* Whh1 = (const float*)d_in[6];
  const float* bih1 = (const float*)d_in[7];
  const float* bhh1 = (const float*)d_in[8];
  char* ws = (char*)d_ws;
  if (ws_size < WS_NEEDED) return;   // ~55.7 MB scratch

  dim3 pgrid(NBLK*KS_TOT);
  prep_w<<<pgrid, 64, 0, stream>>>(Whh0, (unsigned short*)(ws + OFF_WHH0));
  prep_w<<<pgrid, 64, 0, stream>>>(Wih1, (unsigned short*)(ws + OFF_WIH1));
  prep_w<<<pgrid, 64, 0, stream>>>(Whh1, (unsigned short*)(ws + OFF_WHH1));
  init_state<<<764, 256, 0, stream>>>(ws);

  gru_persist<<<NBLK, NTHR, 0, stream>>>(ws, x, Wih0, bih0, bhh0, bih1, bhh1);

  write_out<<<600, 256, 0, stream>>>(ws, (float*)d_out);
}

// Round 6
// 7441.708 us; speedup vs baseline: 2.6835x; 1.0202x over previous
//
#include <hip/hip_runtime.h>
#include <hip/hip_bf16.h>

// ---------------------------------------------------------------------------
// 2-layer GRU, H=1200, B=64, T=512, I=30. Output = [h_last_l0, h_last_l1].
// R6: persistent kernel (225 blocks x 512 thr, 1 block/CU via 128KB LDS).
//  - Cross-block state via relaxed AGENT-scope atomics (bypass L1/L2, served
//    by IF$) -> NO acquire buffer_inv / release buffer_wbl2 in the loop.
//    Weights/x/biases stay plain loads -> warm in L2 forever.
//  - Weight fragments pinned via asm("":"+v") -> compiler cannot remat the
//    loads each step; amdgpu_waves_per_eu(2) opens the 256-VGPR budget.
//  - Grid barrier: syncthreads -> s_waitcnt vmcnt(0) -> relaxed flag store
//    -> poll 225 flags (relaxed) -> compiler barrier -> syncthreads.
// Roles: role0 = layer0 step t=s (W_hh0), role1 = gx1 t=s-1 (W_ih1),
//        role2 = layer1 fuse t=s-2 (W_hh1).
// ---------------------------------------------------------------------------

#define Hh 1200
#define HP 1280          // bf16 state row stride; cols >=1200 stay 0
#define TT 512
#define II 30
#define KS_TOT 38        // 38*32 = 1216 >= 1200
#define KS_PW 5          // 8 waves x 5 = 40 k-units (2 zero-padded)
#define NTG 75
#define NBLK 225
#define NTHR 512

typedef __attribute__((ext_vector_type(8))) short short8;
typedef __attribute__((ext_vector_type(4))) float f32x4;

// workspace layout (bytes)
#define SZ_WF 17510400ull            // per matrix: 225*38*1024 elems * 2B
#define OFF_WHH0 0ull
#define OFF_WIH1 SZ_WF
#define OFF_WHH1 (2ull*SZ_WF)
#define OFF_STATE (3ull*SZ_WF)       // 52,531,200
#define SZ_HF 307200ull              // 64*1200 fp32 (final dump, single)
#define SZ_HB 163840ull              // 64*1280 bf16
#define SZ_GX 921600ull              // 64*3600 fp32
#define OFF_H0F OFF_STATE
#define OFF_H1F (OFF_H0F + SZ_HF)
#define OFF_H0B (OFF_H1F + SZ_HF)
#define OFF_H1B (OFF_H0B + 2ull*SZ_HB)
#define OFF_GX  (OFF_H1B + 2ull*SZ_HB)
#define STATE_BYTES (2ull*SZ_HF + 4ull*SZ_HB + 2ull*SZ_GX)   // 3,112,960
#define OFF_BAR (OFF_STATE + STATE_BYTES)
#define WS_NEEDED (OFF_BAR + 16384ull)

__device__ __forceinline__ unsigned short f2bf(float f){
  unsigned u = __float_as_uint(f);
  unsigned r = u + 0x7FFFu + ((u >> 16) & 1u);   // RNE
  return (unsigned short)(r >> 16);
}
__device__ __forceinline__ float bf2f(unsigned short s){
  return __uint_as_float(((unsigned)s) << 16);
}
__device__ __forceinline__ float sigmoid_f(float v){ return 1.f/(1.f + __expf(-v)); }
__device__ __forceinline__ float tanh_f(float v){ float e = __expf(2.f*v); return 1.f - 2.f/(e + 1.f); }
__device__ __forceinline__ unsigned long long pack2f(float a, float b){
  union { float f[2]; unsigned long long u; } v; v.f[0]=a; v.f[1]=b; return v.u;
}
// 16B state read as two 8B agent-scope relaxed atomics (IF$-fresh, no inv).
__device__ __forceinline__ short8 aload16(const unsigned short* p){
  union { unsigned long long u[2]; short8 s; } v;
  const unsigned long long* q = (const unsigned long long*)p;
  v.u[0] = __hip_atomic_load(q,     __ATOMIC_RELAXED, __HIP_MEMORY_SCOPE_AGENT);
  v.u[1] = __hip_atomic_load(q + 1, __ATOMIC_RELAXED, __HIP_MEMORY_SCOPE_AGENT);
  return v.s;
}
__device__ __forceinline__ void aload2f(const float* p, float* f0, float* f1){
  union { unsigned long long u; float f[2]; } v;
  v.u = __hip_atomic_load((const unsigned long long*)p, __ATOMIC_RELAXED, __HIP_MEMORY_SCOPE_AGENT);
  *f0 = v.f[0]; *f1 = v.f[1];
}

// Split W[3600][K<=1200] fp32 -> bf16 hi/lo in MFMA B-fragment order.
__global__ void prep_w(const float* __restrict__ W, unsigned short* __restrict__ Wf){
  int blk = blockIdx.x;
  int nt = blk / KS_TOT, ks = blk - nt*KS_TOT;
  int l = threadIdx.x;
  int n = nt*16 + (l & 15);
  int k0 = ks*32 + (l >> 4)*8;
  alignas(16) unsigned short hi[8];
  alignas(16) unsigned short lo[8];
  #pragma unroll
  for (int j = 0; j < 8; j++){
    int k = k0 + j;
    float w = (k < Hh) ? W[(size_t)n*Hh + k] : 0.f;
    unsigned short h16 = f2bf(w);
    hi[j] = h16;
    lo[j] = f2bf(w - bf2f(h16));
  }
  size_t cbase = ((size_t)(nt*KS_TOT + ks))*1024ull;
  *(short8*)(Wf + cbase + (size_t)l*8)        = *(const short8*)hi;
  *(short8*)(Wf + cbase + 512 + (size_t)l*8)  = *(const short8*)lo;
}

__global__ void init_state(char* __restrict__ ws){
  size_t i = (size_t)blockIdx.x*256 + threadIdx.x;
  size_t n_all = (STATE_BYTES + 16384ull)/16ull;   // state + barrier flags
  if (i < n_all){
    f32x4 z = {0.f,0.f,0.f,0.f};
    ((f32x4*)(ws + OFF_STATE))[i] = z;
  }
}

__global__ void __launch_bounds__(NTHR)
__attribute__((amdgpu_waves_per_eu(2)))
gru_persist(
    char* __restrict__ ws,
    const float* __restrict__ x,
    const float* __restrict__ Wih0,
    const float* __restrict__ bih0, const float* __restrict__ bhh0,
    const float* __restrict__ bih1, const float* __restrict__ bhh1)
{
  const int bid  = blockIdx.x;
  const int role = bid / NTG;
  const int nb   = bid - role*NTG;
  const int tid  = threadIdx.x;
  const int wv   = tid >> 6;
  const int lane = tid & 63;
  const int col  = lane & 15;
  const int kg   = lane >> 4;
  const int ks0  = wv * KS_PW;
  // epilogue mapping: thread -> (batch, column-pair)
  const int eb  = tid >> 3;            // 0..63
  const int ecp = tid & 7;             // col pair 0..7
  const int c0  = ecp*2;
  const int gc0 = nb*16 + c0;          // global column (even)
  const int lastS = (role == 0) ? (TT-1) : (TT+1);

  __shared__ float part[12][8][256];   // 96 KB split-K partials
  __shared__ float red[12][256];       // 12 KB reduced tiles
  __shared__ float xl[64][II];         // role0: x[t]
  __shared__ float wl[48][II];         // role0: W_ih0 slice
  __shared__ float hfl[64][16];        // block-private fp32 h columns

  int* bar_flags = (int*)(ws + OFF_BAR);   // 64B stride per block

  // zero private h state
  for (int i = tid; i < 64*16; i += NTHR) ((float*)hfl)[i] = 0.f;

  // ---- resident weights: 3 gates x 5 ks x {hi,lo} = 30 short8 = 120 regs
  const short8* wt = (const short8*)(ws + ((role==0)?OFF_WHH0:(role==1)?OFF_WIH1:OFF_WHH1));
  short8 wfr[3][KS_PW][2];
  #pragma unroll
  for (int g = 0; g < 3; g++)
    #pragma unroll
    for (int k = 0; k < KS_PW; k++){
      int ks = ks0 + k;
      #pragma unroll
      for (int sp = 0; sp < 2; sp++){
        short8 v = {0,0,0,0,0,0,0,0};
        if (ks < KS_TOT)
          v = wt[((size_t)((g*NTG + nb)*KS_TOT + ks))*128 + sp*64 + lane];
        wfr[g][k][sp] = v;
        // pin: value is now opaque -> cannot be rematerialized by re-loading
        asm("" : "+v"(wfr[g][k][sp]));
      }
    }

  // role0: stage W_ih0 slice (3 gates x 16 cols x 30) into LDS once
  if (role == 0){
    for (int i = tid; i < 48*II; i += NTHR){
      int rl = i/II, c = i - rl*II;
      int g = rl >> 4, cl = rl & 15;
      wl[rl][c] = Wih0[(size_t)(g*Hh + nb*16 + cl)*II + c];
    }
  }

  // per-thread epilogue biases (2 columns each)
  float bIv[3][2] = {{0.f,0.f},{0.f,0.f},{0.f,0.f}};
  float bHv[3][2] = {{0.f,0.f},{0.f,0.f},{0.f,0.f}};
  if (role == 0){
    #pragma unroll
    for (int g = 0; g < 3; g++){
      bIv[g][0] = bih0[g*Hh + gc0]; bIv[g][1] = bih0[g*Hh + gc0 + 1];
      bHv[g][0] = bhh0[g*Hh + gc0]; bHv[g][1] = bhh0[g*Hh + gc0 + 1];
    }
  } else if (role == 1){
    #pragma unroll
    for (int g = 0; g < 3; g++){
      bIv[g][0] = bih1[g*Hh + gc0]; bIv[g][1] = bih1[g*Hh + gc0 + 1];
    }
  } else {
    #pragma unroll
    for (int g = 0; g < 3; g++){
      bHv[g][0] = bhh1[g*Hh + gc0]; bHv[g][1] = bhh1[g*Hh + gc0 + 1];
    }
  }

  for (int s = 0; s < TT + 2; s++){
    const bool active = (role==0) ? (s < TT) : (role==1) ? (s >= 1 && s <= TT) : (s >= 2);
    const int t   = s - role;
    const int par = t & 1;

    if (active){
      const unsigned short* Ab;
      if (role == 0)      Ab = (const unsigned short*)(ws + OFF_H0B + (size_t)par*SZ_HB);
      else if (role == 1) Ab = (const unsigned short*)(ws + OFF_H0B + (size_t)((t+1)&1)*SZ_HB);
      else                Ab = (const unsigned short*)(ws + OFF_H1B + (size_t)par*SZ_HB);

      if (role == 0){
        for (int i = tid; i < 64*II; i += NTHR){
          int b = i/II, c = i - b*II;
          xl[b][c] = x[(size_t)b*(TT*II) + t*II + c];
        }
      }

      f32x4 acc[3][4];
      #pragma unroll
      for (int g = 0; g < 3; g++)
        #pragma unroll
        for (int m = 0; m < 4; m++) acc[g][m] = (f32x4){0.f,0.f,0.f,0.f};

      #pragma unroll
      for (int k = 0; k < KS_PW; k++){
        short8 a[4];
        #pragma unroll
        for (int m = 0; m < 4; m++)
          a[m] = aload16(&Ab[(size_t)(m*16 + col)*HP + (ks0 + k)*32 + kg*8]);
        #pragma unroll
        for (int g = 0; g < 3; g++)
          #pragma unroll
          for (int m = 0; m < 4; m++){
            acc[g][m] = __builtin_amdgcn_mfma_f32_16x16x32_bf16(a[m], wfr[g][k][0], acc[g][m], 0,0,0);
            acc[g][m] = __builtin_amdgcn_mfma_f32_16x16x32_bf16(a[m], wfr[g][k][1], acc[g][m], 0,0,0);
          }
      }
      #pragma unroll
      for (int g = 0; g < 3; g++)
        #pragma unroll
        for (int m = 0; m < 4; m++)
          *(f32x4*)&part[g*4 + m][wv][lane*4] = acc[g][m];
    }
    __syncthreads();

    if (active){
      #pragma unroll
      for (int r = 0; r < 6; r++){
        int o = r*NTHR + tid;
        int tile = o >> 8, e = o & 255;
        float v = part[tile][0][e] + part[tile][1][e] + part[tile][2][e] + part[tile][3][e]
                + part[tile][4][e] + part[tile][5][e] + part[tile][6][e] + part[tile][7][e];
        red[tile][e] = v;
      }
    }
    __syncthreads();

    if (active){
      const int mt = eb >> 4, dr = eb & 15;
      const int e0 = ((dr>>2)<<6) | (c0<<2) | (dr&3);   // C-frag index, col c0
      if (role == 1){
        float* gxo = (float*)(ws + OFF_GX + (size_t)par*SZ_GX);
        #pragma unroll
        for (int g = 0; g < 3; g++){
          float v0 = red[g*4+mt][e0]     + bIv[g][0];
          float v1 = red[g*4+mt][e0 + 4] + bIv[g][1];
          __hip_atomic_store((unsigned long long*)&gxo[(size_t)eb*3600 + g*Hh + gc0],
                             pack2f(v0, v1), __ATOMIC_RELAXED, __HIP_MEMORY_SCOPE_AGENT);
        }
      } else {
        float gxv[3][2];
        if (role == 0){
          #pragma unroll
          for (int g = 0; g < 3; g++)
            #pragma unroll
            for (int j = 0; j < 2; j++){
              float sum = bIv[g][j];
              #pragma unroll
              for (int i = 0; i < II; i++) sum += wl[g*16 + c0 + j][i] * xl[eb][i];
              gxv[g][j] = sum;
            }
        } else {
          const float* gxi = (const float*)(ws + OFF_GX + (size_t)par*SZ_GX);
          #pragma unroll
          for (int g = 0; g < 3; g++)
            aload2f(&gxi[(size_t)eb*3600 + g*Hh + gc0], &gxv[g][0], &gxv[g][1]);
        }
        unsigned short* hbout = (unsigned short*)(ws + ((role==0)?OFF_H0B:OFF_H1B)
                                                   + (size_t)(par^1)*SZ_HB);
        float hq[2];
        unsigned short hb[2];
        #pragma unroll
        for (int j = 0; j < 2; j++){
          int e = e0 + j*4;
          float rr = sigmoid_f(red[mt][e]     + gxv[0][j] + bHv[0][j]);
          float zz = sigmoid_f(red[4+mt][e]   + gxv[1][j] + bHv[1][j]);
          float nn = tanh_f(gxv[2][j] + rr*(red[8+mt][e] + bHv[2][j]));
          float hold = hfl[eb][c0 + j];
          float hn = (1.f - zz)*nn + zz*hold;
          hfl[eb][c0 + j] = hn;
          hq[j] = hn;
          hb[j] = f2bf(hn);
        }
        unsigned pk = (unsigned)hb[0] | ((unsigned)hb[1] << 16);
        __hip_atomic_store((unsigned*)&hbout[(size_t)eb*HP + gc0], pk,
                           __ATOMIC_RELAXED, __HIP_MEMORY_SCOPE_AGENT);
        if (s == lastS){
          float* hfin = (float*)(ws + ((role==0)?OFF_H0F:OFF_H1F));
          hfin[(size_t)eb*Hh + gc0]     = hq[0];
          hfin[(size_t)eb*Hh + gc0 + 1] = hq[1];
        }
      }
    }

    // -------- grid barrier, fence-free (all shared data is IF$-coherent) ---
    __syncthreads();   // each wave: s_waitcnt vmcnt(0) before s_barrier -> all
                       // block stores complete at the coherence point
    if (tid == 0){
      asm volatile("s_waitcnt vmcnt(0)" ::: "memory");
      __hip_atomic_store(&bar_flags[bid*16], s+1, __ATOMIC_RELAXED, __HIP_MEMORY_SCOPE_AGENT);
    }
    if (tid < NBLK){
      while (__hip_atomic_load(&bar_flags[tid*16], __ATOMIC_RELAXED, __HIP_MEMORY_SCOPE_AGENT) < s+1)
        __builtin_amdgcn_s_sleep(1);
    }
    asm volatile("" ::: "memory");
    __syncthreads();
  }
}

__global__ void write_out(const char* __restrict__ ws, float* __restrict__ out){
  int i = blockIdx.x*256 + threadIdx.x;
  if (i < 76800)        out[i] = *(const float*)(ws + OFF_H0F + (size_t)i*4);
  else if (i < 153600)  out[i] = *(const float*)(ws + OFF_H1F + (size_t)(i - 76800)*4);
}

extern "C" void kernel_launch(void* const* d_in, const int* in_sizes, int n_in,
                              void* d_out, int out_size, void* d_ws, size_t ws_size,
                              hipStream_t stream)
{
  const float* x    = (const float*)d_in[0];
  const float* Wih0 = (const float*)d_in[1];
  const float* Whh0 = (const float*)d_in[2];
  const float* bih0 = (const float*)d_in[3];
  const float* bhh0 = (const float*)d_in[4];
  const float* Wih1 = (const float*)d_in[5];
  const float* Whh1 = (const float*)d_in[6];
  const float* bih1 = (const float*)d_in[7];
  const float* bhh1 = (const float*)d_in[8];
  char* ws = (char*)d_ws;
  if (ws_size < WS_NEEDED) return;   // ~55.7 MB scratch

  dim3 pgrid(NBLK*KS_TOT);
  prep_w<<<pgrid, 64, 0, stream>>>(Whh0, (unsigned short*)(ws + OFF_WHH0));
  prep_w<<<pgrid, 64, 0, stream>>>(Wih1, (unsigned short*)(ws + OFF_WIH1));
  prep_w<<<pgrid, 64, 0, stream>>>(Whh1, (unsigned short*)(ws + OFF_WHH1));
  init_state<<<764, 256, 0, stream>>>(ws);

  gru_persist<<<NBLK, NTHR, 0, stream>>>(ws, x, Wih0, bih0, bhh0, bih1, bhh1);

  write_out<<<600, 256, 0, stream>>>(ws, (float*)d_out);
}